// Round 1
// baseline (341.736 us; speedup 1.0000x reference)
//
#include <hip/hip_runtime.h>

// Problem constants
// B=2, T=2048, C=2048, H=16, KH=4, D=128, rep=4

typedef __attribute__((ext_vector_type(8))) short bf16x8;
typedef __attribute__((ext_vector_type(4))) float f32x4;

__device__ __forceinline__ unsigned short f2bf(float f) {
  union { float f; unsigned u; } v; v.f = f;
  unsigned u = v.u;
  u += 0x7fffu + ((u >> 16) & 1u);   // RNE
  return (unsigned short)(u >> 16);
}
__device__ __forceinline__ float bf2f(unsigned short h) {
  union { unsigned u; float f; } v; v.u = ((unsigned)h) << 16;
  return v.f;
}

// ---------------------------------------------------------------------------
// fp32 -> bf16 cast, 4-wide
__global__ void cvt_f32_bf16(const float* __restrict__ src,
                             unsigned short* __restrict__ dst, long n4) {
  long i = (long)blockIdx.x * blockDim.x + threadIdx.x;
  const long stride = (long)gridDim.x * blockDim.x;
  for (; i < n4; i += stride) {
    const float4 vv = ((const float4*)src)[i];
    ushort4 o;
    o.x = f2bf(vv.x); o.y = f2bf(vv.y); o.z = f2bf(vv.z); o.w = f2bf(vv.w);
    ((ushort4*)dst)[i] = o;
  }
}

// ---------------------------------------------------------------------------
// NT GEMM: C[M,N] = A[M,K] * B[N,K]^T, bf16 in, fp32 accum.
// 128x128 tile, BK=64, 4 waves (2x2), each wave 64x64 (4x4 16x16 frags).
template <int OUT_BF16>
__global__ __launch_bounds__(256)
void gemm_nt(const unsigned short* __restrict__ A,
             const unsigned short* __restrict__ Bm,
             void* __restrict__ Cp, int M, int N, int K) {
  __shared__ unsigned short As[128][72];  // pad 8 -> 2-way bank pattern (free)
  __shared__ unsigned short Bs[128][72];
  const int nbn = N >> 7;
  int wg = blockIdx.x;
  { // XCD swizzle; all our grids are multiples of 8 -> bijective
    const int cpx = (int)gridDim.x >> 3;
    wg = (wg & 7) * cpx + (wg >> 3);
  }
  const int m0 = (wg / nbn) << 7, n0 = (wg % nbn) << 7;
  const int tid = threadIdx.x;
  const int lane = tid & 63, wid = tid >> 6;
  const int lr = lane & 15, lg = lane >> 4;
  const int wm = (wid >> 1) << 6, wn = (wid & 1) << 6;
  f32x4 acc[4][4] = {};
  for (int k0 = 0; k0 < K; k0 += 64) {
    #pragma unroll
    for (int p = 0; p < 4; ++p) {
      const int id = (p << 8) + tid;
      const int r = id >> 3, c8 = (id & 7) << 3;
      *(uint4*)(&As[r][c8]) = *(const uint4*)(A + (size_t)(m0 + r) * K + k0 + c8);
      *(uint4*)(&Bs[r][c8]) = *(const uint4*)(Bm + (size_t)(n0 + r) * K + k0 + c8);
    }
    __syncthreads();
    #pragma unroll
    for (int kk = 0; kk < 2; ++kk) {
      const int ko = (kk << 5) + (lg << 3);
      bf16x8 af[4], bfr[4];
      #pragma unroll
      for (int mf = 0; mf < 4; ++mf)
        af[mf] = *(const bf16x8*)(&As[wm + (mf << 4) + lr][ko]);
      #pragma unroll
      for (int nf = 0; nf < 4; ++nf)
        bfr[nf] = *(const bf16x8*)(&Bs[wn + (nf << 4) + lr][ko]);
      #pragma unroll
      for (int mf = 0; mf < 4; ++mf)
        #pragma unroll
        for (int nf = 0; nf < 4; ++nf)
          acc[mf][nf] = __builtin_amdgcn_mfma_f32_16x16x32_bf16(
              af[mf], bfr[nf], acc[mf][nf], 0, 0, 0);
    }
    __syncthreads();
  }
  #pragma unroll
  for (int mf = 0; mf < 4; ++mf) {
    #pragma unroll
    for (int nf = 0; nf < 4; ++nf) {
      const int m = m0 + wm + (mf << 4) + (lg << 2);
      const int n = n0 + wn + (nf << 4) + lr;
      #pragma unroll
      for (int i = 0; i < 4; ++i) {
        if constexpr (OUT_BF16)
          ((unsigned short*)Cp)[(size_t)(m + i) * N + n] = f2bf(acc[mf][nf][i]);
        else
          ((float*)Cp)[(size_t)(m + i) * N + n] = acc[mf][nf][i];
      }
    }
  }
}

// ---------------------------------------------------------------------------
// Per-(b,t,head) RMSNorm + RoPE for q and k; packs head-major bf16.
// grid: (B*T)*20 blocks of 128 threads (heads 0..15 = q, 16..19 = k)
__global__ __launch_bounds__(128)
void norm_rope(const unsigned short* __restrict__ qkv,  // (B*T, 3072) bf16
               const float* __restrict__ cosb, const float* __restrict__ sinb,
               const float* __restrict__ qw, const float* __restrict__ kw,
               unsigned short* __restrict__ Qb,   // (B,H,T,D)
               unsigned short* __restrict__ Kb) { // (B,KH,T,D)
  const int blk = blockIdx.x;
  const int hh = blk % 20;
  const int bt = blk / 20;
  const int d = threadIdx.x;
  const bool isq = hh < 16;
  const int col = isq ? (hh << 7) + d : 2048 + ((hh - 16) << 7) + d;
  const float v = bf2f(qkv[(size_t)bt * 3072 + col]);
  float ss = v * v;
  #pragma unroll
  for (int off = 1; off < 64; off <<= 1) ss += __shfl_xor(ss, off);
  __shared__ float red[2];
  __shared__ float row[128];
  if ((d & 63) == 0) red[d >> 6] = ss;
  __syncthreads();
  const float rms = rsqrtf((red[0] + red[1]) * (1.0f / 128.0f) + 1e-6f);
  const float nv = v * rms * (isq ? qw[d] : kw[d]);
  row[d] = nv;
  __syncthreads();
  const float partner = (d < 64) ? -row[d + 64] : row[d - 64];
  const float o = nv * cosb[(size_t)bt * 128 + d] + partner * sinb[(size_t)bt * 128 + d];
  const int b = bt >> 11, t = bt & 2047;
  if (isq)
    Qb[((size_t)(b * 16 + hh) * 2048 + t) * 128 + d] = f2bf(o);
  else
    Kb[((size_t)(b * 4 + (hh - 16)) * 2048 + t) * 128 + d] = f2bf(o);
}

// ---------------------------------------------------------------------------
// V transpose+cast: qkv v-columns (B,T,KH,D) -> Vt (B,KH,D,T) bf16
// grid: (B*KH, T/64, D/64), 256 threads, 64x64 LDS tile
__global__ __launch_bounds__(256)
void v_trans(const unsigned short* __restrict__ qkv, unsigned short* __restrict__ Vt) {
  __shared__ unsigned short tile[64][66];  // 66: conflict-free transposed read
  const int b = blockIdx.x >> 2, h = blockIdx.x & 3;
  const int t0 = blockIdx.y << 6, d0 = blockIdx.z << 6;
  const int tid = threadIdx.x;
  #pragma unroll
  for (int p = 0; p < 16; ++p) {
    const int id = (p << 8) + tid;
    const int r = id >> 6, c = id & 63;  // r = t, c = d
    tile[r][c] = qkv[(size_t)(b * 2048 + t0 + r) * 3072 + 2560 + (h << 7) + d0 + c];
  }
  __syncthreads();
  #pragma unroll
  for (int p = 0; p < 16; ++p) {
    const int id = (p << 8) + tid;
    const int r = id >> 6, c = id & 63;  // r = d, c = t
    Vt[(size_t)((b * 4 + h) * 128 + d0 + r) * 2048 + t0 + c] = tile[c][r];
  }
}

// ---------------------------------------------------------------------------
// Causal GQA flash attention. grid (B*H, T/64), 256 threads (4 waves),
// wave w owns q rows [q0+16w, q0+16w+16). KV blocks of 64.
__global__ __launch_bounds__(256)
void attn_fwd(const unsigned short* __restrict__ Qb,  // (B,H,T,D)
              const unsigned short* __restrict__ Kb,  // (B,KH,T,D)
              const unsigned short* __restrict__ Vt,  // (B,KH,D,T)
              unsigned short* __restrict__ Y) {       // (B,T,H,D)
  __shared__ unsigned short Ks[64][136];
  __shared__ unsigned short Vs[128][72];
  __shared__ unsigned short Ps[4][16][72];
  const int bh = blockIdx.x;
  const int b = bh >> 4, h = bh & 15;
  const int qb = blockIdx.y;
  const int q0 = qb << 6;
  const int tid = threadIdx.x;
  const int lane = tid & 63, wv = tid >> 6;
  const int lr = lane & 15, lg = lane >> 4;
  const int hk = h >> 2;  // rep = 4
  const unsigned short* Qp =
      Qb + (size_t)((b * 16 + h) * 2048 + q0 + wv * 16 + lr) * 128;
  bf16x8 aq[4];
  #pragma unroll
  for (int ks = 0; ks < 4; ++ks)
    aq[ks] = *(const bf16x8*)(Qp + (ks << 5) + (lg << 3));
  const unsigned short* Kp = Kb + (size_t)(b * 4 + hk) * 2048 * 128;
  const unsigned short* Vp = Vt + (size_t)(b * 4 + hk) * 128 * 2048;
  float m_i[4] = {-1e30f, -1e30f, -1e30f, -1e30f};
  float l_i[4] = {0.f, 0.f, 0.f, 0.f};
  f32x4 acc[8] = {};
  for (int kb = 0; kb <= qb; ++kb) {
    const int k0 = kb << 6;
    #pragma unroll
    for (int p = 0; p < 4; ++p) {
      const int id = (p << 8) + tid;
      { const int r = id >> 4, c8 = (id & 15) << 3;  // K: 64 x 128
        *(uint4*)(&Ks[r][c8]) = *(const uint4*)(Kp + (size_t)(k0 + r) * 128 + c8); }
      { const int r = id >> 3, c8 = (id & 7) << 3;   // Vt: 128 x 64
        *(uint4*)(&Vs[r][c8]) = *(const uint4*)(Vp + (size_t)r * 2048 + k0 + c8); }
    }
    __syncthreads();
    // S = Q K^T  (16 x 64 per wave)
    f32x4 s[4] = {};
    #pragma unroll
    for (int nf = 0; nf < 4; ++nf)
      #pragma unroll
      for (int ks = 0; ks < 4; ++ks) {
        const bf16x8 bk = *(const bf16x8*)(&Ks[(nf << 4) + lr][(ks << 5) + (lg << 3)]);
        s[nf] = __builtin_amdgcn_mfma_f32_16x16x32_bf16(aq[ks], bk, s[nf], 0, 0, 0);
      }
    const float sc = 0.08838834764831845f;  // 1/sqrt(128)
    const bool domask = (kb == qb);
    #pragma unroll
    for (int i = 0; i < 4; ++i) {
      const int qrow = q0 + wv * 16 + lg * 4 + i;
      float s0 = s[0][i] * sc, s1 = s[1][i] * sc, s2 = s[2][i] * sc, s3 = s[3][i] * sc;
      if (domask) {
        if (k0 + 0 + lr > qrow) s0 = -1e30f;
        if (k0 + 16 + lr > qrow) s1 = -1e30f;
        if (k0 + 32 + lr > qrow) s2 = -1e30f;
        if (k0 + 48 + lr > qrow) s3 = -1e30f;
      }
      float mx = fmaxf(fmaxf(s0, s1), fmaxf(s2, s3));
      mx = fmaxf(mx, __shfl_xor(mx, 1));
      mx = fmaxf(mx, __shfl_xor(mx, 2));
      mx = fmaxf(mx, __shfl_xor(mx, 4));
      mx = fmaxf(mx, __shfl_xor(mx, 8));
      const float mn = fmaxf(m_i[i], mx);
      const float r = __expf(m_i[i] - mn);
      m_i[i] = mn;
      const float p0 = __expf(s0 - mn), p1 = __expf(s1 - mn);
      const float p2 = __expf(s2 - mn), p3 = __expf(s3 - mn);
      float se = p0 + p1 + p2 + p3;
      se += __shfl_xor(se, 1);
      se += __shfl_xor(se, 2);
      se += __shfl_xor(se, 4);
      se += __shfl_xor(se, 8);
      l_i[i] = l_i[i] * r + se;
      #pragma unroll
      for (int df = 0; df < 8; ++df) acc[df][i] *= r;
      // P round-trip through per-wave LDS to re-layout into A-fragments
      Ps[wv][lg * 4 + i][0 + lr]  = f2bf(p0);
      Ps[wv][lg * 4 + i][16 + lr] = f2bf(p1);
      Ps[wv][lg * 4 + i][32 + lr] = f2bf(p2);
      Ps[wv][lg * 4 + i][48 + lr] = f2bf(p3);
    }
    const bf16x8 ap0 = *(const bf16x8*)(&Ps[wv][lr][lg << 3]);
    const bf16x8 ap1 = *(const bf16x8*)(&Ps[wv][lr][32 + (lg << 3)]);
    #pragma unroll
    for (int df = 0; df < 8; ++df) {
      const bf16x8 bv0 = *(const bf16x8*)(&Vs[(df << 4) + lr][(lg << 3)]);
      acc[df] = __builtin_amdgcn_mfma_f32_16x16x32_bf16(ap0, bv0, acc[df], 0, 0, 0);
      const bf16x8 bv1 = *(const bf16x8*)(&Vs[(df << 4) + lr][32 + (lg << 3)]);
      acc[df] = __builtin_amdgcn_mfma_f32_16x16x32_bf16(ap1, bv1, acc[df], 0, 0, 0);
    }
    __syncthreads();
  }
  #pragma unroll
  for (int df = 0; df < 8; ++df) {
    #pragma unroll
    for (int i = 0; i < 4; ++i) {
      const int t = q0 + wv * 16 + lg * 4 + i;
      Y[(((size_t)b * 2048 + t) * 16 + h) * 128 + (df << 4) + lr] =
          f2bf(acc[df][i] / l_i[i]);
    }
  }
}

// ---------------------------------------------------------------------------
extern "C" void kernel_launch(void* const* d_in, const int* in_sizes, int n_in,
                              void* d_out, int out_size, void* d_ws, size_t ws_size,
                              hipStream_t stream) {
  const float* x    = (const float*)d_in[0];
  const float* cosb = (const float*)d_in[1];
  const float* sinb = (const float*)d_in[2];
  const float* Wq   = (const float*)d_in[3];
  const float* Wk   = (const float*)d_in[4];
  const float* Wv   = (const float*)d_in[5];
  const float* Wo   = (const float*)d_in[6];
  const float* qw   = (const float*)d_in[7];
  const float* kw   = (const float*)d_in[8];
  char* ws = (char*)d_ws;
  // Workspace layout (84 MB total):
  unsigned short* xb   = (unsigned short*)(ws);                       // 16MB x bf16, later reused as Y
  unsigned short* Wcat = (unsigned short*)(ws + (16ull << 20));       // 12MB [Wq;Wk;Wv] bf16 (3072,2048)
  unsigned short* Wob  = (unsigned short*)(ws + (28ull << 20));       // 8MB Wo bf16
  unsigned short* qkv  = (unsigned short*)(ws + (36ull << 20));       // 24MB (4096,3072) bf16
  unsigned short* Qb   = (unsigned short*)(ws + (60ull << 20));       // 16MB (B,H,T,D)
  unsigned short* Kb   = (unsigned short*)(ws + (76ull << 20));       // 4MB  (B,KH,T,D)
  unsigned short* Vt   = (unsigned short*)(ws + (80ull << 20));       // 4MB  (B,KH,D,T)

  cvt_f32_bf16<<<2048, 256, 0, stream>>>(x, xb, (long)(4096 * 2048 / 4));
  cvt_f32_bf16<<<2048, 256, 0, stream>>>(Wq, Wcat, (long)(2048 * 2048 / 4));
  cvt_f32_bf16<<<512, 256, 0, stream>>>(Wk, Wcat + 2048 * 2048, (long)(512 * 2048 / 4));
  cvt_f32_bf16<<<512, 256, 0, stream>>>(Wv, Wcat + 2560 * 2048, (long)(512 * 2048 / 4));
  cvt_f32_bf16<<<2048, 256, 0, stream>>>(Wo, Wob, (long)(2048 * 2048 / 4));

  // qkv = x @ [Wq;Wk;Wv]^T   (M=4096, N=3072, K=2048)
  gemm_nt<1><<<768, 256, 0, stream>>>(xb, Wcat, qkv, 4096, 3072, 2048);
  // RMSNorm + RoPE -> head-major Q,K
  norm_rope<<<2 * 2048 * 20, 128, 0, stream>>>(qkv, cosb, sinb, qw, kw, Qb, Kb);
  // V -> transposed bf16
  v_trans<<<dim3(8, 32, 2), 256, 0, stream>>>(qkv, Vt);
  // attention -> Y (reuses xb)
  attn_fwd<<<dim3(32, 32), 256, 0, stream>>>(Qb, Kb, Vt, xb);
  // out = Y @ Wo^T  (M=4096, N=2048, K=2048), fp32 out
  gemm_nt<0><<<512, 256, 0, stream>>>(xb, Wob, d_out, 4096, 2048, 2048);
}

// Round 2
// 285.905 us; speedup vs baseline: 1.1953x; 1.1953x over previous
//
#include <hip/hip_runtime.h>

// B=2, T=2048, C=2048, H=16, KH=4, D=128, rep=4

typedef __attribute__((ext_vector_type(8))) short bf16x8;
typedef __attribute__((ext_vector_type(4))) float f32x4;

__device__ __forceinline__ unsigned short f2bf(float f) {
  union { float f; unsigned u; } v; v.f = f;
  unsigned u = v.u;
  u += 0x7fffu + ((u >> 16) & 1u);   // RNE
  return (unsigned short)(u >> 16);
}
__device__ __forceinline__ float bf2f(unsigned short h) {
  union { unsigned u; float f; } v; v.u = ((unsigned)h) << 16;
  return v.f;
}

// global -> LDS async copy, 16B per lane. LDS dest is wave-uniform base;
// HW writes lane l at base + 16*l. Source addr is per-lane.
__device__ __forceinline__ void gl_lds16(const void* g, void* l) {
  __builtin_amdgcn_global_load_lds(
      (const __attribute__((address_space(1))) unsigned int*)(unsigned long long)g,
      (__attribute__((address_space(3))) unsigned int*)(unsigned int)(unsigned long long)l,
      16, 0, 0);
}

// ---------------------------------------------------------------------------
// fp32 -> bf16 cast, 4-wide
__global__ void cvt_f32_bf16(const float* __restrict__ src,
                             unsigned short* __restrict__ dst, long n4) {
  long i = (long)blockIdx.x * blockDim.x + threadIdx.x;
  const long stride = (long)gridDim.x * blockDim.x;
  for (; i < n4; i += stride) {
    const float4 vv = ((const float4*)src)[i];
    ushort4 o;
    o.x = f2bf(vv.x); o.y = f2bf(vv.y); o.z = f2bf(vv.z); o.w = f2bf(vv.w);
    ((ushort4*)dst)[i] = o;
  }
}

// ---------------------------------------------------------------------------
// NT GEMM (m97 structure): C[M,N] = A[M,K] * B[N,K]^T, bf16 in, fp32 accum.
// 128x128 tile, BK=64, 4 waves (2x2), global_load_lds width-16 staging,
// linear LDS (required by global_load_lds).
template <int OUT_BF16>
__global__ __launch_bounds__(256)
void gemm_nt(const unsigned short* __restrict__ A,
             const unsigned short* __restrict__ Bm,
             void* __restrict__ Cp, int M, int N, int K) {
  __shared__ unsigned short As[128 * 64];
  __shared__ unsigned short Bs[128 * 64];
  const int nbn = N >> 7;
  int wg = blockIdx.x;
  { // XCD swizzle; grids are multiples of 8 -> bijective
    const int cpx = (int)gridDim.x >> 3;
    wg = (wg & 7) * cpx + (wg >> 3);
  }
  const int m0 = (wg / nbn) << 7, n0 = (wg % nbn) << 7;
  const int tid = threadIdx.x;
  const int lane = tid & 63, wid = tid >> 6;
  const int lr = lane & 15, lg = lane >> 4;
  const int wm = (wid >> 1) << 6, wn = (wid & 1) << 6;
  // staging geometry: chunk = 1KB = 8 rows x 128B; wave wid stages chunks 4w..4w+3
  const int srow = (lane >> 3);          // row within chunk
  const int scol = (lane & 7) << 3;      // ushort col
  f32x4 acc[4][4] = {};
  for (int k0 = 0; k0 < K; k0 += 64) {
    #pragma unroll
    for (int i = 0; i < 4; ++i) {
      const int c = (wid << 2) + i;
      const int r = (c << 3) + srow;
      gl_lds16(A + (size_t)(m0 + r) * K + k0 + scol, &As[c << 9]);
      gl_lds16(Bm + (size_t)(n0 + r) * K + k0 + scol, &Bs[c << 9]);
    }
    __syncthreads();
    #pragma unroll
    for (int kk = 0; kk < 2; ++kk) {
      const int ko = (kk << 5) + (lg << 3);
      bf16x8 af[4], bfr[4];
      #pragma unroll
      for (int mf = 0; mf < 4; ++mf)
        af[mf] = *(const bf16x8*)(&As[(wm + (mf << 4) + lr) * 64 + ko]);
      #pragma unroll
      for (int nf = 0; nf < 4; ++nf)
        bfr[nf] = *(const bf16x8*)(&Bs[(wn + (nf << 4) + lr) * 64 + ko]);
      #pragma unroll
      for (int mf = 0; mf < 4; ++mf)
        #pragma unroll
        for (int nf = 0; nf < 4; ++nf)
          acc[mf][nf] = __builtin_amdgcn_mfma_f32_16x16x32_bf16(
              af[mf], bfr[nf], acc[mf][nf], 0, 0, 0);
    }
    __syncthreads();
  }
  #pragma unroll
  for (int mf = 0; mf < 4; ++mf) {
    #pragma unroll
    for (int nf = 0; nf < 4; ++nf) {
      const int m = m0 + wm + (mf << 4) + (lg << 2);
      const int n = n0 + wn + (nf << 4) + lr;
      #pragma unroll
      for (int i = 0; i < 4; ++i) {
        if constexpr (OUT_BF16)
          ((unsigned short*)Cp)[(size_t)(m + i) * N + n] = f2bf(acc[mf][nf][i]);
        else
          ((float*)Cp)[(size_t)(m + i) * N + n] = acc[mf][nf][i];
      }
    }
  }
}

// ---------------------------------------------------------------------------
// RMSNorm + RoPE, wave-per-row, vectorized (ushort2/float2).
// rows = B*T*20 (heads 0..15 = q, 16..19 = k); 4 waves/block.
__global__ __launch_bounds__(256)
void norm_rope(const unsigned short* __restrict__ qkv,  // (B*T, 3072) bf16
               const float* __restrict__ cosb, const float* __restrict__ sinb,
               const float* __restrict__ qw, const float* __restrict__ kw,
               unsigned short* __restrict__ Qb,   // (B,H,T,D)
               unsigned short* __restrict__ Kb) { // (B,KH,T,D)
  const int wv = threadIdx.x >> 6, l = threadIdx.x & 63;
  const int rr = blockIdx.x * 4 + wv;
  const int hh = rr % 20, bt = rr / 20;
  const bool isq = hh < 16;
  // q heads: cols hh*128; k heads (hh=16..19): cols 2048+(hh-16)*128 == hh*128
  const ushort2 u = *(const ushort2*)(qkv + (size_t)bt * 3072 + (hh << 7) + 2 * l);
  const float v0 = bf2f(u.x), v1 = bf2f(u.y);
  float ss = v0 * v0 + v1 * v1;
  #pragma unroll
  for (int off = 1; off < 64; off <<= 1) ss += __shfl_xor(ss, off);
  const float rms = rsqrtf(ss * (1.0f / 128.0f) + 1e-6f);
  const float* w = isq ? qw : kw;
  const float2 w2 = *(const float2*)(w + 2 * l);
  const float n0 = v0 * rms * w2.x, n1 = v1 * rms * w2.y;
  const float sx0 = __shfl_xor(n0, 32), sx1 = __shfl_xor(n1, 32);
  const float p0 = (l < 32) ? -sx0 : sx0;
  const float p1 = (l < 32) ? -sx1 : sx1;
  const float2 c2 = *(const float2*)(cosb + (size_t)bt * 128 + 2 * l);
  const float2 s2 = *(const float2*)(sinb + (size_t)bt * 128 + 2 * l);
  ushort2 o;
  o.x = f2bf(n0 * c2.x + p0 * s2.x);
  o.y = f2bf(n1 * c2.y + p1 * s2.y);
  const int b = bt >> 11, t = bt & 2047;
  if (isq)
    *(ushort2*)(Qb + (((size_t)(b * 16 + hh) * 2048 + t) << 7) + 2 * l) = o;
  else
    *(ushort2*)(Kb + (((size_t)(b * 4 + (hh - 16)) * 2048 + t) << 7) + 2 * l) = o;
}

// ---------------------------------------------------------------------------
// V transpose+cast: qkv v-columns (B,T,KH,D) -> Vt (B,KH,D,T) bf16
__global__ __launch_bounds__(256)
void v_trans(const unsigned short* __restrict__ qkv, unsigned short* __restrict__ Vt) {
  __shared__ unsigned short tile[64][66];
  const int b = blockIdx.x >> 2, h = blockIdx.x & 3;
  const int t0 = blockIdx.y << 6, d0 = blockIdx.z << 6;
  const int tid = threadIdx.x;
  #pragma unroll
  for (int p = 0; p < 16; ++p) {
    const int id = (p << 8) + tid;
    const int r = id >> 6, c = id & 63;  // r = t, c = d
    tile[r][c] = qkv[(size_t)(b * 2048 + t0 + r) * 3072 + 2560 + (h << 7) + d0 + c];
  }
  __syncthreads();
  #pragma unroll
  for (int p = 0; p < 16; ++p) {
    const int id = (p << 8) + tid;
    const int r = id >> 6, c = id & 63;  // r = d, c = t
    Vt[(size_t)((b * 4 + h) * 128 + d0 + r) * 2048 + t0 + c] = tile[c][r];
  }
}

// ---------------------------------------------------------------------------
// Causal GQA flash attention, PAIRED q-tiles for load balance.
// grid (B*H=32, P=16); block p handles q-tiles {p, 31-p} (64 rows each),
// sharing staged K/V blocks. 4 waves; wave wv owns rows [16wv,16wv+16) of
// EACH tile. K/V staged via global_load_lds with pre-swizzled source
// (XOR (row&7)<<4), read back with the same XOR -> b128-floor banking.
__global__ __launch_bounds__(256)
void attn_fwd(const unsigned short* __restrict__ Qb,  // (B,H,T,D)
              const unsigned short* __restrict__ Kb,  // (B,KH,T,D)
              const unsigned short* __restrict__ Vt,  // (B,KH,D,T)
              unsigned short* __restrict__ Y) {       // (B,T,H,D)
  __shared__ unsigned short Ks[64 * 128];   // 16KB, rows of 256B
  __shared__ unsigned short Vs[128 * 64];   // 16KB, rows of 128B
  __shared__ unsigned short Ps[4][16][72];
  const int bh = blockIdx.x;
  const int b = bh >> 4, h = bh & 15, hk = h >> 2;
  const int p = blockIdx.y;
  const int qtj[2] = {p, 31 - p};
  const int tid = threadIdx.x;
  const int lane = tid & 63, wv = tid >> 6;
  const int lr = lane & 15, lg = lane >> 4;
  const unsigned short* Kp = Kb + (size_t)(b * 4 + hk) * 2048 * 128;
  const unsigned short* Vp = Vt + (size_t)(b * 4 + hk) * 128 * 2048;
  bf16x8 aq[2][4];
  #pragma unroll
  for (int j = 0; j < 2; ++j) {
    const unsigned short* Qp =
        Qb + (size_t)((b * 16 + h) * 2048 + qtj[j] * 64 + wv * 16 + lr) * 128;
    #pragma unroll
    for (int ks = 0; ks < 4; ++ks)
      aq[j][ks] = *(const bf16x8*)(Qp + (ks << 5) + (lg << 3));
  }
  float m_i[2][4] = {{-1e30f, -1e30f, -1e30f, -1e30f},
                     {-1e30f, -1e30f, -1e30f, -1e30f}};
  float l_i[2][4] = {};
  f32x4 acc[2][8] = {};
  // staging per-lane geometry
  const int kr_in = (lane >> 4), kcb = (lane & 15) << 4;   // K chunk: 4 rows x 256B
  const int vr_in = (lane >> 3), vcb = (lane & 7) << 4;    // V chunk: 8 rows x 128B
  const int nkb = 32 - p;
  for (int kb = 0; kb < nkb; ++kb) {
    const int k0 = kb << 6;
    #pragma unroll
    for (int i = 0; i < 4; ++i) {
      const int c = (wv << 2) + i;
      { // K tile: 64 x 128 ushort
        const int r = (c << 2) + kr_in;
        const int sw = kcb ^ ((r & 7) << 4);
        gl_lds16(Kp + (size_t)(k0 + r) * 128 + (sw >> 1), &Ks[c << 9]);
      }
      { // V tile: 128 x 64 ushort
        const int r = (c << 3) + vr_in;
        const int sw = vcb ^ ((r & 7) << 4);
        gl_lds16(Vp + (size_t)r * 2048 + k0 + (sw >> 1), &Vs[c << 9]);
      }
    }
    __syncthreads();
    #pragma unroll
    for (int j = 0; j < 2; ++j) {
      if (kb > qtj[j]) continue;   // uniform branch; only j=0 can skip
      // S = Q K^T (16 x 64 per wave)
      f32x4 s[4] = {};
      __builtin_amdgcn_s_setprio(1);
      #pragma unroll
      for (int nf = 0; nf < 4; ++nf) {
        const int row = (nf << 4) + lr;
        const int swb = (row & 7) << 4;
        #pragma unroll
        for (int ks = 0; ks < 4; ++ks) {
          const bf16x8 bk = *(const bf16x8*)(
              (const char*)Ks + (row << 8) + (((ks << 6) + (lg << 4)) ^ swb));
          s[nf] = __builtin_amdgcn_mfma_f32_16x16x32_bf16(aq[j][ks], bk, s[nf], 0, 0, 0);
        }
      }
      __builtin_amdgcn_s_setprio(0);
      const float sc = 0.08838834764831845f;  // 1/sqrt(128)
      const bool domask = (kb == qtj[j]);
      #pragma unroll
      for (int i = 0; i < 4; ++i) {
        const int qrow = qtj[j] * 64 + wv * 16 + lg * 4 + i;
        float s0 = s[0][i] * sc, s1 = s[1][i] * sc;
        float s2 = s[2][i] * sc, s3 = s[3][i] * sc;
        if (domask) {
          if (k0 + 0 + lr > qrow) s0 = -1e30f;
          if (k0 + 16 + lr > qrow) s1 = -1e30f;
          if (k0 + 32 + lr > qrow) s2 = -1e30f;
          if (k0 + 48 + lr > qrow) s3 = -1e30f;
        }
        float mx = fmaxf(fmaxf(s0, s1), fmaxf(s2, s3));
        mx = fmaxf(mx, __shfl_xor(mx, 1));
        mx = fmaxf(mx, __shfl_xor(mx, 2));
        mx = fmaxf(mx, __shfl_xor(mx, 4));
        mx = fmaxf(mx, __shfl_xor(mx, 8));
        const float mn = fmaxf(m_i[j][i], mx);
        const float r = __expf(m_i[j][i] - mn);
        m_i[j][i] = mn;
        const float p0 = __expf(s0 - mn), p1 = __expf(s1 - mn);
        const float p2 = __expf(s2 - mn), p3 = __expf(s3 - mn);
        float se = p0 + p1 + p2 + p3;
        se += __shfl_xor(se, 1);
        se += __shfl_xor(se, 2);
        se += __shfl_xor(se, 4);
        se += __shfl_xor(se, 8);
        l_i[j][i] = l_i[j][i] * r + se;
        #pragma unroll
        for (int df = 0; df < 8; ++df) acc[j][df][i] *= r;
        Ps[wv][lg * 4 + i][0 + lr]  = f2bf(p0);
        Ps[wv][lg * 4 + i][16 + lr] = f2bf(p1);
        Ps[wv][lg * 4 + i][32 + lr] = f2bf(p2);
        Ps[wv][lg * 4 + i][48 + lr] = f2bf(p3);
      }
      const bf16x8 ap0 = *(const bf16x8*)(&Ps[wv][lr][lg << 3]);
      const bf16x8 ap1 = *(const bf16x8*)(&Ps[wv][lr][32 + (lg << 3)]);
      __builtin_amdgcn_s_setprio(1);
      #pragma unroll
      for (int df = 0; df < 8; ++df) {
        const int row = (df << 4) + lr;
        const int swb = (row & 7) << 4;
        const bf16x8 bv0 = *(const bf16x8*)(
            (const char*)Vs + (row << 7) + (((lg << 4) ^ swb)));
        acc[j][df] = __builtin_amdgcn_mfma_f32_16x16x32_bf16(ap0, bv0, acc[j][df], 0, 0, 0);
        const bf16x8 bv1 = *(const bf16x8*)(
            (const char*)Vs + (row << 7) + ((64 + (lg << 4)) ^ swb));
        acc[j][df] = __builtin_amdgcn_mfma_f32_16x16x32_bf16(ap1, bv1, acc[j][df], 0, 0, 0);
      }
      __builtin_amdgcn_s_setprio(0);
    }
    __syncthreads();
  }
  #pragma unroll
  for (int j = 0; j < 2; ++j) {
    float inv[4];
    #pragma unroll
    for (int i = 0; i < 4; ++i) inv[i] = 1.0f / l_i[j][i];
    #pragma unroll
    for (int df = 0; df < 8; ++df) {
      #pragma unroll
      for (int i = 0; i < 4; ++i) {
        const int t = qtj[j] * 64 + wv * 16 + lg * 4 + i;
        Y[(((size_t)b * 2048 + t) * 16 + h) * 128 + (df << 4) + lr] =
            f2bf(acc[j][df][i] * inv[i]);
      }
    }
  }
}

// ---------------------------------------------------------------------------
extern "C" void kernel_launch(void* const* d_in, const int* in_sizes, int n_in,
                              void* d_out, int out_size, void* d_ws, size_t ws_size,
                              hipStream_t stream) {
  const float* x    = (const float*)d_in[0];
  const float* cosb = (const float*)d_in[1];
  const float* sinb = (const float*)d_in[2];
  const float* Wq   = (const float*)d_in[3];
  const float* Wk   = (const float*)d_in[4];
  const float* Wv   = (const float*)d_in[5];
  const float* Wo   = (const float*)d_in[6];
  const float* qw   = (const float*)d_in[7];
  const float* kw   = (const float*)d_in[8];
  char* ws = (char*)d_ws;
  unsigned short* xb   = (unsigned short*)(ws);                       // 16MB x bf16, later reused as Y
  unsigned short* Wcat = (unsigned short*)(ws + (16ull << 20));       // 12MB [Wq;Wk;Wv] bf16
  unsigned short* Wob  = (unsigned short*)(ws + (28ull << 20));       // 8MB Wo bf16
  unsigned short* qkv  = (unsigned short*)(ws + (36ull << 20));       // 24MB (4096,3072) bf16
  unsigned short* Qb   = (unsigned short*)(ws + (60ull << 20));       // 16MB (B,H,T,D)
  unsigned short* Kb   = (unsigned short*)(ws + (76ull << 20));       // 4MB  (B,KH,T,D)
  unsigned short* Vt   = (unsigned short*)(ws + (80ull << 20));       // 4MB  (B,KH,D,T)

  cvt_f32_bf16<<<2048, 256, 0, stream>>>(x, xb, (long)(4096 * 2048 / 4));
  cvt_f32_bf16<<<2048, 256, 0, stream>>>(Wq, Wcat, (long)(2048 * 2048 / 4));
  cvt_f32_bf16<<<512, 256, 0, stream>>>(Wk, Wcat + 2048 * 2048, (long)(512 * 2048 / 4));
  cvt_f32_bf16<<<512, 256, 0, stream>>>(Wv, Wcat + 2560 * 2048, (long)(512 * 2048 / 4));
  cvt_f32_bf16<<<2048, 256, 0, stream>>>(Wo, Wob, (long)(2048 * 2048 / 4));

  // qkv = x @ [Wq;Wk;Wv]^T   (M=4096, N=3072, K=2048)
  gemm_nt<1><<<768, 256, 0, stream>>>(xb, Wcat, qkv, 4096, 3072, 2048);
  // RMSNorm + RoPE -> head-major Q,K  (B*T*20 rows, 4 waves/block)
  norm_rope<<<2 * 2048 * 20 / 4, 256, 0, stream>>>(qkv, cosb, sinb, qw, kw, Qb, Kb);
  // V -> transposed bf16
  v_trans<<<dim3(8, 32, 2), 256, 0, stream>>>(qkv, Vt);
  // attention -> Y (reuses xb); paired q-tiles
  attn_fwd<<<dim3(32, 16), 256, 0, stream>>>(Qb, Kb, Vt, xb);
  // out = Y @ Wo^T  (M=4096, N=2048, K=2048), fp32 out
  gemm_nt<0><<<512, 256, 0, stream>>>(xb, Wob, d_out, 4096, 2048, 2048);
}

// Round 3
// 271.780 us; speedup vs baseline: 1.2574x; 1.0520x over previous
//
#include <hip/hip_runtime.h>

// B=2, T=2048, C=2048, H=16, KH=4, D=128, rep=4

typedef __attribute__((ext_vector_type(8))) short bf16x8;
typedef __attribute__((ext_vector_type(4))) float f32x4;

__device__ __forceinline__ unsigned short f2bf(float f) {
  union { float f; unsigned u; } v; v.f = f;
  unsigned u = v.u;
  u += 0x7fffu + ((u >> 16) & 1u);   // RNE
  return (unsigned short)(u >> 16);
}
__device__ __forceinline__ float bf2f(unsigned short h) {
  union { unsigned u; float f; } v; v.u = ((unsigned)h) << 16;
  return v.f;
}

// global -> LDS async copy, 16B per lane. LDS dest must be wave-uniform;
// HW writes lane l at dest + 16*l. Source addr is per-lane.
__device__ __forceinline__ void gl_lds16(const void* g, void* l) {
  __builtin_amdgcn_global_load_lds(
      (const __attribute__((address_space(1))) unsigned int*)(unsigned long long)g,
      (__attribute__((address_space(3))) unsigned int*)(unsigned int)(unsigned long long)l,
      16, 0, 0);
}

// ---------------------------------------------------------------------------
// fp32 -> bf16 cast, 4-wide
__global__ void cvt_f32_bf16(const float* __restrict__ src,
                             unsigned short* __restrict__ dst, long n4) {
  long i = (long)blockIdx.x * blockDim.x + threadIdx.x;
  const long stride = (long)gridDim.x * blockDim.x;
  for (; i < n4; i += stride) {
    const float4 vv = ((const float4*)src)[i];
    ushort4 o;
    o.x = f2bf(vv.x); o.y = f2bf(vv.y); o.z = f2bf(vv.z); o.w = f2bf(vv.w);
    ((ushort4*)dst)[i] = o;
  }
}

// ---------------------------------------------------------------------------
// 256x256 8-phase NT GEMM (m201-style): C[M,N] = A[M,K]*B[N,K]^T, bf16 in.
// 512 threads = 8 waves (2M x 4N). BK=64, double-buffered 128KB LDS.
// Per K-tile: 4 phases (C-quadrants), each {ds_read 12xb128 | stage half-tile
// | barrier | lgkmcnt0 | 16 MFMA | counted vmcnt | barrier}.
// LDS tiles are [256 rows][64 k] bf16, rows 128B, XOR-chunk swizzle
// (chunk ^= row&7) applied on the global SOURCE of global_load_lds and on
// the ds_read address (both-sides involution).
#define PHASE(QM, QN, PF, GATE)                                               \
  {                                                                           \
    bf16x8 af[4][2], bg[2][2];                                                \
    _Pragma("unroll") for (int r = 0; r < 4; ++r) {                           \
      const char* pa = ldsc + curb + (((QM)*128 + arow0 + r*16) << 7);        \
      af[r][0] = *(const bf16x8*)(pa + csw0);                                 \
      af[r][1] = *(const bf16x8*)(pa + csw1);                                 \
    }                                                                         \
    _Pragma("unroll") for (int n = 0; n < 2; ++n) {                           \
      const char* pb = ldsc + curb + 32768 + (((QN)*128 + brow0 + n*16) << 7);\
      bg[n][0] = *(const bf16x8*)(pb + csw0);                                 \
      bg[n][1] = *(const bf16x8*)(pb + csw1);                                 \
    }                                                                         \
    PF                                                                        \
    __builtin_amdgcn_s_barrier();                                             \
    asm volatile("s_waitcnt lgkmcnt(0)" ::: "memory");                        \
    __builtin_amdgcn_sched_barrier(0);                                        \
    __builtin_amdgcn_s_setprio(1);                                            \
    _Pragma("unroll") for (int r = 0; r < 4; ++r)                             \
      _Pragma("unroll") for (int n = 0; n < 2; ++n) {                         \
        acc[(QM)*4+r][(QN)*2+n] = __builtin_amdgcn_mfma_f32_16x16x32_bf16(    \
            af[r][0], bg[n][0], acc[(QM)*4+r][(QN)*2+n], 0, 0, 0);            \
        acc[(QM)*4+r][(QN)*2+n] = __builtin_amdgcn_mfma_f32_16x16x32_bf16(    \
            af[r][1], bg[n][1], acc[(QM)*4+r][(QN)*2+n], 0, 0, 0);            \
      }                                                                       \
    __builtin_amdgcn_s_setprio(0);                                            \
    GATE                                                                      \
    __builtin_amdgcn_s_barrier();                                             \
  }

template <int OUT_BF16>
__global__ __launch_bounds__(512, 2)
void gemm256(const unsigned short* __restrict__ A,
             const unsigned short* __restrict__ Bm,
             void* __restrict__ Cp, int M, int N, int K) {
  __shared__ __align__(16) char ldsc[131072];  // [2 buf][A 32KB | B 32KB]
  const int nbn = N >> 8;
  int wg = blockIdx.x;
  { // XCD swizzle; grids are multiples of 8 -> bijective
    const int cpx = (int)gridDim.x >> 3;
    wg = (wg & 7) * cpx + (wg >> 3);
  }
  const int m0 = (wg / nbn) << 8, n0 = (wg % nbn) << 8;
  const int tid = threadIdx.x;
  const int lane = tid & 63, wid = tid >> 6;
  const int lr = lane & 15, lg = lane >> 4;
  const int wm = wid >> 2, wn = wid & 3;  // 2 x 4 wave grid
  // ds_read per-lane constants (col byte ^ swizzle; row&7 == lr&7)
  const int csw0 = (lg << 4) ^ ((lr & 7) << 4);
  const int csw1 = (64 + (lg << 4)) ^ ((lr & 7) << 4);
  const int arow0 = (wm << 6) + lr;
  const int brow0 = (wn << 5) + lr;
  // staging per-lane constants (source pre-swizzled: chunk ^= row&7)
  const int srowL = tid >> 3;  // 0..63
  const int scol = ((tid & 7) ^ (srowL & 7)) << 3;
  const unsigned short* Asrc = A + (size_t)(m0 + srowL) * K + scol;
  const unsigned short* Bsrc = Bm + (size_t)(n0 + srowL) * K + scol;
  const int sdst = wid << 10;
  const int NT = K >> 6;
  f32x4 acc[8][4] = {};
  // prologue: stage tile 0 into buf0, order A0 B0 A1 B1
  gl_lds16(Asrc, ldsc + sdst);
  gl_lds16(Asrc + (size_t)64 * K, ldsc + 8192 + sdst);
  gl_lds16(Bsrc, ldsc + 32768 + sdst);
  gl_lds16(Bsrc + (size_t)64 * K, ldsc + 40960 + sdst);
  gl_lds16(Asrc + (size_t)128 * K, ldsc + 16384 + sdst);
  gl_lds16(Asrc + (size_t)192 * K, ldsc + 24576 + sdst);
  gl_lds16(Bsrc + (size_t)128 * K, ldsc + 49152 + sdst);
  gl_lds16(Bsrc + (size_t)192 * K, ldsc + 57344 + sdst);
  asm volatile("s_waitcnt vmcnt(4)" ::: "memory");
  __builtin_amdgcn_s_barrier();

  for (int t = 0; t < NT; ++t) {
    const int curb = (t & 1) << 16;
    const int nxtb = curb ^ 65536;
    const size_t kn = (size_t)(t + 1) << 6;
    const bool pf = (t + 1) < NT;
    PHASE(0, 0,
      if (pf) { gl_lds16(Asrc + kn, ldsc + nxtb + sdst);
                gl_lds16(Asrc + (size_t)64 * K + kn, ldsc + nxtb + 8192 + sdst); },
      if (pf) { asm volatile("s_waitcnt vmcnt(2)" ::: "memory"); }
      else    { asm volatile("s_waitcnt vmcnt(0)" ::: "memory"); } )
    PHASE(1, 0,
      if (pf) { gl_lds16(Bsrc + kn, ldsc + nxtb + 32768 + sdst);
                gl_lds16(Bsrc + (size_t)64 * K + kn, ldsc + nxtb + 40960 + sdst); }, )
    PHASE(0, 1,
      if (pf) { gl_lds16(Asrc + (size_t)128 * K + kn, ldsc + nxtb + 16384 + sdst);
                gl_lds16(Asrc + (size_t)192 * K + kn, ldsc + nxtb + 24576 + sdst); }, )
    PHASE(1, 1,
      if (pf) { gl_lds16(Bsrc + (size_t)128 * K + kn, ldsc + nxtb + 49152 + sdst);
                gl_lds16(Bsrc + (size_t)192 * K + kn, ldsc + nxtb + 57344 + sdst); },
      if (pf) { asm volatile("s_waitcnt vmcnt(4)" ::: "memory"); } )
  }
  // epilogue: C write (register-only, no sync needed)
  #pragma unroll
  for (int mi = 0; mi < 8; ++mi) {
    const int mrow = m0 + ((mi >> 2) << 7) + (wm << 6) + ((mi & 3) << 4) + (lg << 2);
    #pragma unroll
    for (int ni = 0; ni < 4; ++ni) {
      const int ncol = n0 + ((ni >> 1) << 7) + (wn << 5) + ((ni & 1) << 4) + lr;
      #pragma unroll
      for (int i = 0; i < 4; ++i) {
        if constexpr (OUT_BF16)
          ((unsigned short*)Cp)[(size_t)(mrow + i) * N + ncol] = f2bf(acc[mi][ni][i]);
        else
          ((float*)Cp)[(size_t)(mrow + i) * N + ncol] = acc[mi][ni][i];
      }
    }
  }
}

// ---------------------------------------------------------------------------
// RMSNorm + RoPE, wave-per-row, vectorized (ushort2/float2).
__global__ __launch_bounds__(256)
void norm_rope(const unsigned short* __restrict__ qkv,  // (B*T, 3072) bf16
               const float* __restrict__ cosb, const float* __restrict__ sinb,
               const float* __restrict__ qw, const float* __restrict__ kw,
               unsigned short* __restrict__ Qb,   // (B,H,T,D)
               unsigned short* __restrict__ Kb) { // (B,KH,T,D)
  const int wv = threadIdx.x >> 6, l = threadIdx.x & 63;
  const int rr = blockIdx.x * 4 + wv;
  const int hh = rr % 20, bt = rr / 20;
  const bool isq = hh < 16;
  const ushort2 u = *(const ushort2*)(qkv + (size_t)bt * 3072 + (hh << 7) + 2 * l);
  const float v0 = bf2f(u.x), v1 = bf2f(u.y);
  float ss = v0 * v0 + v1 * v1;
  #pragma unroll
  for (int off = 1; off < 64; off <<= 1) ss += __shfl_xor(ss, off);
  const float rms = rsqrtf(ss * (1.0f / 128.0f) + 1e-6f);
  const float* w = isq ? qw : kw;
  const float2 w2 = *(const float2*)(w + 2 * l);
  const float n0 = v0 * rms * w2.x, n1 = v1 * rms * w2.y;
  const float sx0 = __shfl_xor(n0, 32), sx1 = __shfl_xor(n1, 32);
  const float p0 = (l < 32) ? -sx0 : sx0;
  const float p1 = (l < 32) ? -sx1 : sx1;
  const float2 c2 = *(const float2*)(cosb + (size_t)bt * 128 + 2 * l);
  const float2 s2 = *(const float2*)(sinb + (size_t)bt * 128 + 2 * l);
  ushort2 o;
  o.x = f2bf(n0 * c2.x + p0 * s2.x);
  o.y = f2bf(n1 * c2.y + p1 * s2.y);
  const int b = bt >> 11, t = bt & 2047;
  if (isq)
    *(ushort2*)(Qb + (((size_t)(b * 16 + hh) * 2048 + t) << 7) + 2 * l) = o;
  else
    *(ushort2*)(Kb + (((size_t)(b * 4 + (hh - 16)) * 2048 + t) << 7) + 2 * l) = o;
}

// ---------------------------------------------------------------------------
// V transpose+cast: qkv v-columns (B,T,KH,D) -> Vt (B,KH,D,T) bf16
__global__ __launch_bounds__(256)
void v_trans(const unsigned short* __restrict__ qkv, unsigned short* __restrict__ Vt) {
  __shared__ unsigned short tile[64][66];
  const int b = blockIdx.x >> 2, h = blockIdx.x & 3;
  const int t0 = blockIdx.y << 6, d0 = blockIdx.z << 6;
  const int tid = threadIdx.x;
  #pragma unroll
  for (int p = 0; p < 16; ++p) {
    const int id = (p << 8) + tid;
    const int r = id >> 6, c = id & 63;  // r = t, c = d
    tile[r][c] = qkv[(size_t)(b * 2048 + t0 + r) * 3072 + 2560 + (h << 7) + d0 + c];
  }
  __syncthreads();
  #pragma unroll
  for (int p = 0; p < 16; ++p) {
    const int id = (p << 8) + tid;
    const int r = id >> 6, c = id & 63;  // r = d, c = t
    Vt[(size_t)((b * 4 + h) * 128 + d0 + r) * 2048 + t0 + c] = tile[c][r];
  }
}

// ---------------------------------------------------------------------------
// Causal GQA flash attention, PAIRED q-tiles for load balance.
__global__ __launch_bounds__(256)
void attn_fwd(const unsigned short* __restrict__ Qb,  // (B,H,T,D)
              const unsigned short* __restrict__ Kb,  // (B,KH,T,D)
              const unsigned short* __restrict__ Vt,  // (B,KH,D,T)
              unsigned short* __restrict__ Y) {       // (B,T,H,D)
  __shared__ unsigned short Ks[64 * 128];
  __shared__ unsigned short Vs[128 * 64];
  __shared__ unsigned short Ps[4][16][72];
  const int bh = blockIdx.x;
  const int b = bh >> 4, h = bh & 15, hk = h >> 2;
  const int p = blockIdx.y;
  const int qtj[2] = {p, 31 - p};
  const int tid = threadIdx.x;
  const int lane = tid & 63, wv = tid >> 6;
  const int lr = lane & 15, lg = lane >> 4;
  const unsigned short* Kp = Kb + (size_t)(b * 4 + hk) * 2048 * 128;
  const unsigned short* Vp = Vt + (size_t)(b * 4 + hk) * 128 * 2048;
  bf16x8 aq[2][4];
  #pragma unroll
  for (int j = 0; j < 2; ++j) {
    const unsigned short* Qp =
        Qb + (size_t)((b * 16 + h) * 2048 + qtj[j] * 64 + wv * 16 + lr) * 128;
    #pragma unroll
    for (int ks = 0; ks < 4; ++ks)
      aq[j][ks] = *(const bf16x8*)(Qp + (ks << 5) + (lg << 3));
  }
  float m_i[2][4] = {{-1e30f, -1e30f, -1e30f, -1e30f},
                     {-1e30f, -1e30f, -1e30f, -1e30f}};
  float l_i[2][4] = {};
  f32x4 acc[2][8] = {};
  const int kr_in = (lane >> 4), kcb = (lane & 15) << 4;   // K chunk: 4 rows x 256B
  const int vr_in = (lane >> 3), vcb = (lane & 7) << 4;    // V chunk: 8 rows x 128B
  const int nkb = 32 - p;
  for (int kb = 0; kb < nkb; ++kb) {
    const int k0 = kb << 6;
    #pragma unroll
    for (int i = 0; i < 4; ++i) {
      const int c = (wv << 2) + i;
      { const int r = (c << 2) + kr_in;
        const int sw = kcb ^ ((r & 7) << 4);
        gl_lds16(Kp + (size_t)(k0 + r) * 128 + (sw >> 1), &Ks[c << 9]); }
      { const int r = (c << 3) + vr_in;
        const int sw = vcb ^ ((r & 7) << 4);
        gl_lds16(Vp + (size_t)r * 2048 + k0 + (sw >> 1), &Vs[c << 9]); }
    }
    __syncthreads();
    #pragma unroll
    for (int j = 0; j < 2; ++j) {
      if (kb > qtj[j]) continue;   // uniform; only j=0 can skip
      f32x4 s[4] = {};
      __builtin_amdgcn_s_setprio(1);
      #pragma unroll
      for (int nf = 0; nf < 4; ++nf) {
        const int row = (nf << 4) + lr;
        const int swb = (row & 7) << 4;
        #pragma unroll
        for (int ks = 0; ks < 4; ++ks) {
          const bf16x8 bk = *(const bf16x8*)(
              (const char*)Ks + (row << 8) + (((ks << 6) + (lg << 4)) ^ swb));
          s[nf] = __builtin_amdgcn_mfma_f32_16x16x32_bf16(aq[j][ks], bk, s[nf], 0, 0, 0);
        }
      }
      __builtin_amdgcn_s_setprio(0);
      const float sc = 0.08838834764831845f;  // 1/sqrt(128)
      const bool domask = (kb == qtj[j]);
      #pragma unroll
      for (int i = 0; i < 4; ++i) {
        const int qrow = qtj[j] * 64 + wv * 16 + lg * 4 + i;
        float s0 = s[0][i] * sc, s1 = s[1][i] * sc;
        float s2 = s[2][i] * sc, s3 = s[3][i] * sc;
        if (domask) {
          if (k0 + 0 + lr > qrow) s0 = -1e30f;
          if (k0 + 16 + lr > qrow) s1 = -1e30f;
          if (k0 + 32 + lr > qrow) s2 = -1e30f;
          if (k0 + 48 + lr > qrow) s3 = -1e30f;
        }
        float mx = fmaxf(fmaxf(s0, s1), fmaxf(s2, s3));
        mx = fmaxf(mx, __shfl_xor(mx, 1));
        mx = fmaxf(mx, __shfl_xor(mx, 2));
        mx = fmaxf(mx, __shfl_xor(mx, 4));
        mx = fmaxf(mx, __shfl_xor(mx, 8));
        const float mn = fmaxf(m_i[j][i], mx);
        const float r = __expf(m_i[j][i] - mn);
        m_i[j][i] = mn;
        const float p0 = __expf(s0 - mn), p1 = __expf(s1 - mn);
        const float p2 = __expf(s2 - mn), p3 = __expf(s3 - mn);
        float se = p0 + p1 + p2 + p3;
        se += __shfl_xor(se, 1);
        se += __shfl_xor(se, 2);
        se += __shfl_xor(se, 4);
        se += __shfl_xor(se, 8);
        l_i[j][i] = l_i[j][i] * r + se;
        #pragma unroll
        for (int df = 0; df < 8; ++df) acc[j][df][i] *= r;
        Ps[wv][lg * 4 + i][0 + lr]  = f2bf(p0);
        Ps[wv][lg * 4 + i][16 + lr] = f2bf(p1);
        Ps[wv][lg * 4 + i][32 + lr] = f2bf(p2);
        Ps[wv][lg * 4 + i][48 + lr] = f2bf(p3);
      }
      const bf16x8 ap0 = *(const bf16x8*)(&Ps[wv][lr][lg << 3]);
      const bf16x8 ap1 = *(const bf16x8*)(&Ps[wv][lr][32 + (lg << 3)]);
      __builtin_amdgcn_s_setprio(1);
      #pragma unroll
      for (int df = 0; df < 8; ++df) {
        const int row = (df << 4) + lr;
        const int swb = (row & 7) << 4;
        const bf16x8 bv0 = *(const bf16x8*)(
            (const char*)Vs + (row << 7) + (((lg << 4) ^ swb)));
        acc[j][df] = __builtin_amdgcn_mfma_f32_16x16x32_bf16(ap0, bv0, acc[j][df], 0, 0, 0);
        const bf16x8 bv1 = *(const bf16x8*)(
            (const char*)Vs + (row << 7) + ((64 + (lg << 4)) ^ swb));
        acc[j][df] = __builtin_amdgcn_mfma_f32_16x16x32_bf16(ap1, bv1, acc[j][df], 0, 0, 0);
      }
      __builtin_amdgcn_s_setprio(0);
    }
    __syncthreads();
  }
  #pragma unroll
  for (int j = 0; j < 2; ++j) {
    float inv[4];
    #pragma unroll
    for (int i = 0; i < 4; ++i) inv[i] = 1.0f / l_i[j][i];
    #pragma unroll
    for (int df = 0; df < 8; ++df) {
      #pragma unroll
      for (int i = 0; i < 4; ++i) {
        const int t = qtj[j] * 64 + wv * 16 + lg * 4 + i;
        Y[(((size_t)b * 2048 + t) * 16 + h) * 128 + (df << 4) + lr] =
            f2bf(acc[j][df][i] * inv[i]);
      }
    }
  }
}

// ---------------------------------------------------------------------------
extern "C" void kernel_launch(void* const* d_in, const int* in_sizes, int n_in,
                              void* d_out, int out_size, void* d_ws, size_t ws_size,
                              hipStream_t stream) {
  const float* x    = (const float*)d_in[0];
  const float* cosb = (const float*)d_in[1];
  const float* sinb = (const float*)d_in[2];
  const float* Wq   = (const float*)d_in[3];
  const float* Wk   = (const float*)d_in[4];
  const float* Wv   = (const float*)d_in[5];
  const float* Wo   = (const float*)d_in[6];
  const float* qw   = (const float*)d_in[7];
  const float* kw   = (const float*)d_in[8];
  char* ws = (char*)d_ws;
  unsigned short* xb   = (unsigned short*)(ws);                       // 16MB x bf16, later reused as Y
  unsigned short* Wcat = (unsigned short*)(ws + (16ull << 20));       // 12MB [Wq;Wk;Wv] bf16
  unsigned short* Wob  = (unsigned short*)(ws + (28ull << 20));       // 8MB Wo bf16
  unsigned short* qkv  = (unsigned short*)(ws + (36ull << 20));       // 24MB (4096,3072) bf16
  unsigned short* Qb   = (unsigned short*)(ws + (60ull << 20));       // 16MB (B,H,T,D)
  unsigned short* Kb   = (unsigned short*)(ws + (76ull << 20));       // 4MB  (B,KH,T,D)
  unsigned short* Vt   = (unsigned short*)(ws + (80ull << 20));       // 4MB  (B,KH,D,T)

  cvt_f32_bf16<<<2048, 256, 0, stream>>>(x, xb, (long)(4096 * 2048 / 4));
  cvt_f32_bf16<<<2048, 256, 0, stream>>>(Wq, Wcat, (long)(2048 * 2048 / 4));
  cvt_f32_bf16<<<512, 256, 0, stream>>>(Wk, Wcat + 2048 * 2048, (long)(512 * 2048 / 4));
  cvt_f32_bf16<<<512, 256, 0, stream>>>(Wv, Wcat + 2560 * 2048, (long)(512 * 2048 / 4));
  cvt_f32_bf16<<<2048, 256, 0, stream>>>(Wo, Wob, (long)(2048 * 2048 / 4));

  // qkv = x @ [Wq;Wk;Wv]^T   (M=4096, N=3072, K=2048): 16x12 = 192 blocks
  gemm256<1><<<192, 512, 0, stream>>>(xb, Wcat, qkv, 4096, 3072, 2048);
  // RMSNorm + RoPE -> head-major Q,K
  norm_rope<<<2 * 2048 * 20 / 4, 256, 0, stream>>>(qkv, cosb, sinb, qw, kw, Qb, Kb);
  // V -> transposed bf16
  v_trans<<<dim3(8, 32, 2), 256, 0, stream>>>(qkv, Vt);
  // attention -> Y (reuses xb); paired q-tiles
  attn_fwd<<<dim3(32, 16), 256, 0, stream>>>(Qb, Kb, Vt, xb);
  // out = Y @ Wo^T  (M=4096, N=2048, K=2048): 16x8 = 128 blocks, fp32 out
  gemm256<0><<<128, 512, 0, stream>>>(xb, Wob, d_out, 4096, 2048, 2048);
}